// Round 1
// baseline (1671.337 us; speedup 1.0000x reference)
//
#include <hip/hip_runtime.h>

// Problem constants
#define NN   8
#define CC   128     // feat channels / out channels
#define CWW  64      // weight channels
#define CIN  192     // C + CW
#define HH   96
#define WW_  96
#define HW   (HH*WW_)      // 9216
#define NB   6
#define TEM  6
#define B36  36            // NB*TEM
#define KF   768           // C*NB

// workspace layout (float offsets)
#define OFF_WT     0                         // 1728*128 = 221184
#define OFF_COEFT  221184                    // 768*128  =  98304
#define OFF_HMID   (221184+98304)            // 8*128*9216 = 9437184
#define OFF_BASES  (OFF_HMID+9437184)        // 8*54*9216  = 3981312
// total floats = 13737984  (~52.4 MiB)

// ---------------------------------------------------------------------------
// Prep: transpose conv1 weights (co,ci,ky,kx)->(r=ci*9+tap, co) and
// coef (co,k)->(k,co) so inner-loop weight loads are lane-coalesced.
__global__ __launch_bounds__(256) void k_prep(const float* __restrict__ w1,
                                              const float* __restrict__ coef,
                                              float* __restrict__ wT,
                                              float* __restrict__ coefT) {
    int i = blockIdx.x * 256 + threadIdx.x;
    if (i < CC * CIN * 9) {
        int co = i / (CIN * 9);
        int r  = i - co * (CIN * 9);
        wT[r * CC + co] = w1[i];
    } else {
        int j = i - CC * CIN * 9;
        if (j < CC * KF) {
            int co = j / KF;
            int k  = j - co * KF;
            coefT[k * CC + co] = coef[j];
        }
    }
}

// ---------------------------------------------------------------------------
// conv1: 3x3, concat(feat[128], weight[64]) -> 128, pad 1, tanh.
// Block: 256 thr = 128 co x 2 pixel-halves; 32-wide row tile per block.
__global__ __launch_bounds__(256) void k_conv1(const float* __restrict__ feat,
                                               const float* __restrict__ wgt,
                                               const float* __restrict__ wT,
                                               const float* __restrict__ b1,
                                               float* __restrict__ hmid) {
    const int wt = blockIdx.x, h = blockIdx.y, n = blockIdx.z;
    const int wbase = wt * 32;
    __shared__ float sIn[32][3][36];     // 32 ch x 3 rows x 34 cols (+pad)
    const int co = threadIdx.x & 127;
    const int ph = threadIdx.x >> 7;     // pixel half: 0 or 1

    float acc[16];
    const float bv = b1[co];
#pragma unroll
    for (int p = 0; p < 16; ++p) acc[p] = bv;

    for (int ch0 = 0; ch0 < CIN; ch0 += 32) {
        __syncthreads();   // previous chunk fully consumed
        for (int i = threadIdx.x; i < 32 * 3 * 34; i += 256) {
            int cc  = i / 102;
            int rem = i - cc * 102;
            int r   = rem / 34;
            int x   = rem - r * 34;
            int ch  = ch0 + cc;
            int hh2 = h - 1 + r;
            int ww2 = wbase - 1 + x;
            float v = 0.f;
            if ((unsigned)hh2 < HH && (unsigned)ww2 < WW_)
                v = (ch < CC) ? feat[((n * CC + ch) * HH + hh2) * WW_ + ww2]
                              : wgt[((n * CWW + (ch - CC)) * HH + hh2) * WW_ + ww2];
            sIn[cc][r][x] = v;
        }
        __syncthreads();

#pragma unroll 4
        for (int cc = 0; cc < 32; ++cc) {
#pragma unroll
            for (int ky = 0; ky < 3; ++ky) {
                float rr[18];
#pragma unroll
                for (int j = 0; j < 18; ++j) rr[j] = sIn[cc][ky][ph * 16 + j];
#pragma unroll
                for (int kx = 0; kx < 3; ++kx) {
                    float wv = wT[((ch0 + cc) * 9 + ky * 3 + kx) * CC + co];
#pragma unroll
                    for (int p = 0; p < 16; ++p)
                        acc[p] = fmaf(wv, rr[p + kx], acc[p]);
                }
            }
        }
    }

    const int wo = wbase + ph * 16;
    float* dst = &hmid[((n * CC + co) * HH + h) * WW_ + wo];
#pragma unroll
    for (int p = 0; p < 16; ++p) dst[p] = tanhf(acc[p]);
}

// ---------------------------------------------------------------------------
// conv2 (1x1, 128->36) + tanh + basis mix (36 -> 54 = 6 bases x 9 taps).
__global__ __launch_bounds__(256) void k_conv2(const float* __restrict__ hmid,
                                               const float* __restrict__ w2,
                                               const float* __restrict__ b2,
                                               const float* __restrict__ bbuf,
                                               float* __restrict__ bases) {
    __shared__ float sW2[B36 * CC];
    __shared__ float sBB[TEM * 9];
    for (int i = threadIdx.x; i < B36 * CC; i += 256) sW2[i] = w2[i];
    if (threadIdx.x < TEM * 9) sBB[threadIdx.x] = bbuf[threadIdx.x];
    __syncthreads();

    const int n   = blockIdx.y;
    const int pix = blockIdx.x * 256 + threadIdx.x;

    float a[B36];
#pragma unroll
    for (int k = 0; k < B36; ++k) a[k] = b2[k];

    const float* hp = &hmid[(size_t)(n * CC) * HW + pix];
    for (int c = 0; c < CC; ++c) {
        float hv = hp[c * HW];
#pragma unroll
        for (int k = 0; k < B36; ++k) a[k] = fmaf(hv, sW2[k * CC + c], a[k]);
    }
#pragma unroll
    for (int k = 0; k < B36; ++k) a[k] = tanhf(a[k]);

    float* bp = &bases[(size_t)(n * 54) * HW + pix];
#pragma unroll
    for (int m = 0; m < NB; ++m) {
#pragma unroll
        for (int l = 0; l < 9; ++l) {
            float s = 0.f;
#pragma unroll
            for (int t = 0; t < TEM; ++t) s = fmaf(a[m * TEM + t], sBB[t * 9 + l], s);
            bp[(m * 9 + l) * HW] = s;
        }
    }
}

// ---------------------------------------------------------------------------
// bases_out (per-pixel 768x9 dot with feat patches) + final 1x1 (K=768) + bias.
// Block: 16 pixels of one row. Stage A fills sBo[768][16] (stride 17),
// stage B is the 128x768 matvec against L2-resident coefT.
__global__ __launch_bounds__(256) void k_final(const float* __restrict__ feat,
                                               const float* __restrict__ bases,
                                               const float* __restrict__ coefT,
                                               const float* __restrict__ bias,
                                               float* __restrict__ out) {
    const int wt = blockIdx.x, h = blockIdx.y, n = blockIdx.z;
    const int w0 = wt * 16;
    __shared__ float sBo[KF][17];   // +1 pad: conflict-free scalar r/w
    __shared__ float sBa[54][16];

    for (int i = threadIdx.x; i < 54 * 16; i += 256) {
        int j = i >> 4, p = i & 15;
        sBa[j][p] = bases[((size_t)(n * 54 + j)) * HW + h * WW_ + w0 + p];
    }
    __syncthreads();

    // stage A: bo[c,m][p] = sum_{ky,kx} bases[m][ky*3+kx][p] * feat[c, h+ky-1, w0+p+kx-1]
    for (int kk = threadIdx.x; kk < KF; kk += 256) {
        int c = kk / 6, m = kk - c * 6;
        float bo[16];
#pragma unroll
        for (int p = 0; p < 16; ++p) bo[p] = 0.f;
        const float* fc = &feat[((size_t)(n * CC + c)) * HW];
#pragma unroll
        for (int ky = 0; ky < 3; ++ky) {
            int hh2 = h - 1 + ky;
            float rr[18];
            if ((unsigned)hh2 < HH) {
#pragma unroll
                for (int x = 0; x < 18; ++x) {
                    int ww2 = w0 - 1 + x;
                    rr[x] = ((unsigned)ww2 < WW_) ? fc[hh2 * WW_ + ww2] : 0.f;
                }
            } else {
#pragma unroll
                for (int x = 0; x < 18; ++x) rr[x] = 0.f;
            }
#pragma unroll
            for (int kx = 0; kx < 3; ++kx) {
                const float* sb = &sBa[m * 9 + ky * 3 + kx][0];
#pragma unroll
                for (int p = 0; p < 16; ++p)
                    bo[p] = fmaf(sb[p], rr[p + kx], bo[p]);
            }
        }
#pragma unroll
        for (int p = 0; p < 16; ++p) sBo[kk][p] = bo[p];
    }
    __syncthreads();

    // stage B: out[co][p] = bias[co] + sum_k coefT[k][co] * sBo[k][p]
    const int p   = threadIdx.x & 15;
    const int cog = threadIdx.x >> 4;    // 0..15
    const int co0 = cog * 8;
    float acc[8];
#pragma unroll
    for (int j = 0; j < 8; ++j) acc[j] = bias[co0 + j];
#pragma unroll 4
    for (int k = 0; k < KF; ++k) {
        float bvv = sBo[k][p];
        const float* cw = &coefT[k * CC + co0];
#pragma unroll
        for (int j = 0; j < 8; ++j) acc[j] = fmaf(bvv, cw[j], acc[j]);
    }
    float* op = &out[((size_t)(n * CC + co0) * HH + h) * WW_ + w0 + p];
#pragma unroll
    for (int j = 0; j < 8; ++j) op[j * HW] = acc[j];
}

// ---------------------------------------------------------------------------
extern "C" void kernel_launch(void* const* d_in, const int* in_sizes, int n_in,
                              void* d_out, int out_size, void* d_ws, size_t ws_size,
                              hipStream_t stream) {
    const float* feat  = (const float*)d_in[0];
    const float* wgt   = (const float*)d_in[1];
    const float* w1    = (const float*)d_in[2];
    const float* b1    = (const float*)d_in[3];
    const float* w2    = (const float*)d_in[4];
    const float* b2    = (const float*)d_in[5];
    const float* bbuf  = (const float*)d_in[6];
    const float* coef  = (const float*)d_in[7];
    const float* bias  = (const float*)d_in[8];
    float* out = (float*)d_out;

    float* ws     = (float*)d_ws;
    float* wT     = ws + OFF_WT;
    float* coefT  = ws + OFF_COEFT;
    float* hmid   = ws + OFF_HMID;
    float* bases  = ws + OFF_BASES;

    // prep transposes: (221184 + 98304) / 256 = 1248 blocks
    k_prep<<<dim3(1248), dim3(256), 0, stream>>>(w1, coef, wT, coefT);

    // conv1: 3 w-tiles x 96 rows x 8 images
    k_conv1<<<dim3(3, HH, NN), dim3(256), 0, stream>>>(feat, wgt, wT, b1, hmid);

    // conv2 + basis mix: 9216/256 = 36 blocks x 8 images
    k_conv2<<<dim3(36, NN), dim3(256), 0, stream>>>(hmid, w2, b2, bbuf, bases);

    // bases_out + final 1x1: 6 w-tiles x 96 rows x 8 images
    k_final<<<dim3(6, HH, NN), dim3(256), 0, stream>>>(feat, bases, coefT, bias, out);
}

// Round 2
// 1419.001 us; speedup vs baseline: 1.1778x; 1.1778x over previous
//
#include <hip/hip_runtime.h>

// Problem constants
#define NN   8
#define CC   128     // feat channels / out channels
#define CWW  64      // weight channels
#define CIN  192     // C + CW
#define HH   96
#define WW_  96
#define HW   (HH*WW_)      // 9216
#define NB   6
#define TEM  6
#define B36  36            // NB*TEM
#define KF   768           // C*NB

// workspace layout (float offsets)
#define OFF_WT     0                         // 1728*128 = 221184
#define OFF_CTM    221184                    // 6*128*128 = 98304  (coef as [m][c][co])
#define OFF_HMID   (221184+98304)            // 8*128*9216 = 9437184 ; later aliased by F (6*128*9216=7077888)
#define OFF_BASES  (OFF_HMID+9437184)        // 8*54*9216  = 3981312
// total floats = 13737984  (~52.4 MiB)

// ---------------------------------------------------------------------------
// Prep: wT[r=ci*9+tap][co] = w1[co][ci][tap];  cTm[m][c][co] = coef[co][c*6+m]
__global__ __launch_bounds__(256) void k_prep(const float* __restrict__ w1,
                                              const float* __restrict__ coef,
                                              float* __restrict__ wT,
                                              float* __restrict__ cTm) {
    int i = blockIdx.x * 256 + threadIdx.x;
    if (i < CC * CIN * 9) {
        int co = i / (CIN * 9);
        int r  = i - co * (CIN * 9);
        wT[r * CC + co] = w1[i];
    } else {
        int j = i - CC * CIN * 9;
        if (j < CC * KF) {
            int co = j / KF;
            int r  = j - co * KF;     // r = c*6+m
            int c  = r / 6;
            int m  = r - c * 6;
            cTm[(m * CC + c) * CC + co] = coef[j];
        }
    }
}

// ---------------------------------------------------------------------------
// conv1: 3x3, concat(feat[128], weight[64]) -> 128, pad 1, tanh.  (unchanged)
__global__ __launch_bounds__(256) void k_conv1(const float* __restrict__ feat,
                                               const float* __restrict__ wgt,
                                               const float* __restrict__ wT,
                                               const float* __restrict__ b1,
                                               float* __restrict__ hmid) {
    const int wt = blockIdx.x, h = blockIdx.y, n = blockIdx.z;
    const int wbase = wt * 32;
    __shared__ float sIn[32][3][36];
    const int co = threadIdx.x & 127;
    const int ph = threadIdx.x >> 7;

    float acc[16];
    const float bv = b1[co];
#pragma unroll
    for (int p = 0; p < 16; ++p) acc[p] = bv;

    for (int ch0 = 0; ch0 < CIN; ch0 += 32) {
        __syncthreads();
        for (int i = threadIdx.x; i < 32 * 3 * 34; i += 256) {
            int cc  = i / 102;
            int rem = i - cc * 102;
            int r   = rem / 34;
            int x   = rem - r * 34;
            int ch  = ch0 + cc;
            int hh2 = h - 1 + r;
            int ww2 = wbase - 1 + x;
            float v = 0.f;
            if ((unsigned)hh2 < HH && (unsigned)ww2 < WW_)
                v = (ch < CC) ? feat[((n * CC + ch) * HH + hh2) * WW_ + ww2]
                              : wgt[((n * CWW + (ch - CC)) * HH + hh2) * WW_ + ww2];
            sIn[cc][r][x] = v;
        }
        __syncthreads();

#pragma unroll 4
        for (int cc = 0; cc < 32; ++cc) {
#pragma unroll
            for (int ky = 0; ky < 3; ++ky) {
                float rr[18];
#pragma unroll
                for (int j = 0; j < 18; ++j) rr[j] = sIn[cc][ky][ph * 16 + j];
#pragma unroll
                for (int kx = 0; kx < 3; ++kx) {
                    float wv = wT[((ch0 + cc) * 9 + ky * 3 + kx) * CC + co];
#pragma unroll
                    for (int p = 0; p < 16; ++p)
                        acc[p] = fmaf(wv, rr[p + kx], acc[p]);
                }
            }
        }
    }

    const int wo = wbase + ph * 16;
    float* dst = &hmid[((n * CC + co) * HH + h) * WW_ + wo];
#pragma unroll
    for (int p = 0; p < 16; ++p) dst[p] = tanhf(acc[p]);
}

// ---------------------------------------------------------------------------
// conv2 (1x1, 128->36) + tanh + basis mix (36 -> 54).  (unchanged)
__global__ __launch_bounds__(256) void k_conv2(const float* __restrict__ hmid,
                                               const float* __restrict__ w2,
                                               const float* __restrict__ b2,
                                               const float* __restrict__ bbuf,
                                               float* __restrict__ bases) {
    __shared__ float sW2[B36 * CC];
    __shared__ float sBB[TEM * 9];
    for (int i = threadIdx.x; i < B36 * CC; i += 256) sW2[i] = w2[i];
    if (threadIdx.x < TEM * 9) sBB[threadIdx.x] = bbuf[threadIdx.x];
    __syncthreads();

    const int n   = blockIdx.y;
    const int pix = blockIdx.x * 256 + threadIdx.x;

    float a[B36];
#pragma unroll
    for (int k = 0; k < B36; ++k) a[k] = b2[k];

    const float* hp = &hmid[(size_t)(n * CC) * HW + pix];
    for (int c = 0; c < CC; ++c) {
        float hv = hp[c * HW];
#pragma unroll
        for (int k = 0; k < B36; ++k) a[k] = fmaf(hv, sW2[k * CC + c], a[k]);
    }
#pragma unroll
    for (int k = 0; k < B36; ++k) a[k] = tanhf(a[k]);

    float* bp = &bases[(size_t)(n * 54) * HW + pix];
#pragma unroll
    for (int m = 0; m < NB; ++m) {
#pragma unroll
        for (int l = 0; l < 9; ++l) {
            float s = 0.f;
#pragma unroll
            for (int t = 0; t < TEM; ++t) s = fmaf(a[m * TEM + t], sBB[t * 9 + l], s);
            bp[(m * 9 + l) * HW] = s;
        }
    }
}

// ---------------------------------------------------------------------------
// F GEMM for one image: F[m][h][w][co] = sum_c cTm[m][c][co] * feat[n,c,h,w]
// grid (6 wtiles of 16px, 96 rows, 3 mpairs), block 256 = 128 co x 2 px-halves.
__global__ __launch_bounds__(256) void k_fm(const float* __restrict__ feat,
                                            const float* __restrict__ cTm,
                                            float* __restrict__ F, int n) {
    const int wt = blockIdx.x, h = blockIdx.y, m0 = blockIdx.z * 2;
    const int w0 = wt * 16;
    __shared__ float sF[CC][16];     // feat[c][w0+p] at row h
    const int co   = threadIdx.x & 127;
    const int half = threadIdx.x >> 7;

    for (int i = threadIdx.x; i < CC * 16; i += 256) {
        int c = i >> 4, p = i & 15;
        sF[c][p] = feat[((size_t)(n * CC + c)) * HW + h * WW_ + w0 + p];
    }
    __syncthreads();

    float acc0[8], acc1[8];
#pragma unroll
    for (int p = 0; p < 8; ++p) { acc0[p] = 0.f; acc1[p] = 0.f; }

    const float* cw0 = &cTm[(size_t)(m0 * CC) * CC + co];
    const float* cw1 = &cTm[(size_t)((m0 + 1) * CC) * CC + co];
#pragma unroll 4
    for (int c = 0; c < CC; ++c) {
        float rr[8];
#pragma unroll
        for (int p = 0; p < 8; ++p) rr[p] = sF[c][half * 8 + p];
        float w0v = cw0[c * CC];
        float w1v = cw1[c * CC];
#pragma unroll
        for (int p = 0; p < 8; ++p) {
            acc0[p] = fmaf(w0v, rr[p], acc0[p]);
            acc1[p] = fmaf(w1v, rr[p], acc1[p]);
        }
    }

    const int wbase = w0 + half * 8;
#pragma unroll
    for (int p = 0; p < 8; ++p) {
        F[(((size_t)(m0 * HH + h)) * WW_ + wbase + p) * CC + co]       = acc0[p];
        F[(((size_t)((m0 + 1) * HH + h)) * WW_ + wbase + p) * CC + co] = acc1[p];
    }
}

// ---------------------------------------------------------------------------
// Combine for one image: out[co,h,w] = bias[co] + sum_{m,dy,dx} bases[m,dy*3+dx,h,w] * F[m,h+dy-1,w+dx-1,co]
// grid (3 wtiles of 32px, 96 rows, 2 co-halves), block 256 = 64 co x 4 px-quarters of 8.
__global__ __launch_bounds__(256) void k_comb(const float* __restrict__ F,
                                              const float* __restrict__ bases,
                                              const float* __restrict__ bias,
                                              float* __restrict__ out, int n) {
    const int wt = blockIdx.x, h = blockIdx.y, coz = blockIdx.z;
    const int w0 = wt * 32;
    __shared__ float sBa[54][32];
    __shared__ float sOut[64][33];

    for (int i = threadIdx.x; i < 54 * 32; i += 256) {
        int j = i >> 5, p = i & 31;
        sBa[j][p] = bases[((size_t)(n * 54 + j)) * HW + h * WW_ + w0 + p];
    }
    __syncthreads();

    const int col  = threadIdx.x & 63;          // local co
    const int co   = coz * 64 + col;
    const int q    = threadIdx.x >> 6;          // px quarter (0..3)
    const int pxb  = q * 8;                     // local px base

    float acc[8];
    const float bv = bias[co];
#pragma unroll
    for (int p = 0; p < 8; ++p) acc[p] = bv;

#pragma unroll
    for (int m = 0; m < NB; ++m) {
#pragma unroll
        for (int dy = 0; dy < 3; ++dy) {
            const int hh2 = h - 1 + dy;
            float rr[10];
            if ((unsigned)hh2 < HH) {
#pragma unroll
                for (int x = 0; x < 10; ++x) {
                    int c2 = w0 + pxb - 1 + x;
                    rr[x] = ((unsigned)c2 < WW_)
                          ? F[(((size_t)(m * HH + hh2)) * WW_ + c2) * CC + co] : 0.f;
                }
            } else {
#pragma unroll
                for (int x = 0; x < 10; ++x) rr[x] = 0.f;
            }
#pragma unroll
            for (int dx = 0; dx < 3; ++dx) {
                const float* sb = &sBa[m * 9 + dy * 3 + dx][pxb];
#pragma unroll
                for (int p = 0; p < 8; ++p)
                    acc[p] = fmaf(sb[p], rr[p + dx], acc[p]);
            }
        }
    }

    // LDS transpose so the global store is pixel-coalesced
#pragma unroll
    for (int p = 0; p < 8; ++p) sOut[col][pxb + p] = acc[p];
    __syncthreads();

    const int sc = threadIdx.x & 31;            // store col (pixel)
#pragma unroll
    for (int it = 0; it < 8; ++it) {
        int row = (threadIdx.x >> 5) + it * 8;  // local co row
        out[((size_t)(n * CC + coz * 64 + row)) * HW + h * WW_ + w0 + sc] = sOut[row][sc];
    }
}

// ---------------------------------------------------------------------------
extern "C" void kernel_launch(void* const* d_in, const int* in_sizes, int n_in,
                              void* d_out, int out_size, void* d_ws, size_t ws_size,
                              hipStream_t stream) {
    const float* feat  = (const float*)d_in[0];
    const float* wgt   = (const float*)d_in[1];
    const float* w1    = (const float*)d_in[2];
    const float* b1    = (const float*)d_in[3];
    const float* w2    = (const float*)d_in[4];
    const float* b2    = (const float*)d_in[5];
    const float* bbuf  = (const float*)d_in[6];
    const float* coef  = (const float*)d_in[7];
    const float* bias  = (const float*)d_in[8];
    float* out = (float*)d_out;

    float* ws     = (float*)d_ws;
    float* wT     = ws + OFF_WT;
    float* cTm    = ws + OFF_CTM;
    float* hmid   = ws + OFF_HMID;
    float* bases  = ws + OFF_BASES;
    float* F      = ws + OFF_HMID;   // aliases hmid (dead after k_conv2); 7.08M < 9.44M floats

    k_prep<<<dim3(1248), dim3(256), 0, stream>>>(w1, coef, wT, cTm);
    k_conv1<<<dim3(3, HH, NN), dim3(256), 0, stream>>>(feat, wgt, wT, b1, hmid);
    k_conv2<<<dim3(36, NN), dim3(256), 0, stream>>>(hmid, w2, b2, bbuf, bases);

    for (int n = 0; n < NN; ++n) {
        k_fm  <<<dim3(6, HH, 3), dim3(256), 0, stream>>>(feat, cTm, F, n);
        k_comb<<<dim3(3, HH, 2), dim3(256), 0, stream>>>(F, bases, bias, out, n);
    }
}

// Round 3
// 1028.821 us; speedup vs baseline: 1.6245x; 1.3792x over previous
//
#include <hip/hip_runtime.h>

// Problem constants
#define NN   8
#define CC   128
#define CWW  64
#define CIN  192
#define HH   96
#define WW_  96
#define HW   (HH*WW_)      // 9216
#define NB   6
#define TEM  6
#define B36  36
#define KF   768

typedef __attribute__((ext_vector_type(8))) short bf16x8;
typedef __attribute__((ext_vector_type(4))) float f32x4;

// workspace layout (float offsets)
#define OFF_A1     0           // 221184 ushorts = 110592 floats (conv1 W frag-packed)
#define OFF_A2     110592      // 98304 ushorts = 49152 floats (coef frag-packed)
#define OFF_BASES  159744      // 8*54*9216 = 3981312 floats
#define OFF_HMID   4141056     // 8*128*9216 = 9437184 floats; F aliases this region
#define FSTRIDE    7077888     // per-image F floats (6*9216*128)
// per-image total: 13578240 floats (54.3 MB). batched needs 60764160 floats (243 MB).

__device__ inline ushort f2bf(float f) {
    union { float f; unsigned u; } x; x.f = f;
    unsigned r = x.u + 0x7FFFu + ((x.u >> 16) & 1u);
    return (ushort)(r >> 16);
}
__device__ inline float fast_tanh(float x) {
    x = fminf(fmaxf(x, -15.f), 15.f);
    float e = __expf(2.f * x);
    float r;
    asm volatile("v_rcp_f32 %0, %1" : "=v"(r) : "v"(e + 1.f));
    return (e - 1.f) * r;
}

// ---------------------------------------------------------------------------
// Prep: pack conv1 weights and coef into MFMA fragment order (bf16).
// A1[((ks*8+mf)*64+l)*8+j] = w1[co=mf*16+(l&15)][ci=kc*32+8*(l>>4)+j][tap], ks=tap*6+kc
// A2[((r*8+cf)*64+l)*8+j]  = coef[co=cf*16+(l&15)][ (ks*32+8*(l>>4)+j)*6+m ], r=m*4+ks
__global__ __launch_bounds__(256) void k_prep(const float* __restrict__ w1,
                                              const float* __restrict__ coef,
                                              ushort* __restrict__ A1,
                                              ushort* __restrict__ A2) {
    int i = blockIdx.x * 256 + threadIdx.x;
    if (i < 221184) {
        int j = i & 7, l = (i >> 3) & 63, mf = (i >> 9) & 7, ks = i >> 12; // ks 0..53
        int kc = ks % 6, tap = ks / 6;
        int co = mf * 16 + (l & 15);
        int ci = kc * 32 + 8 * (l >> 4) + j;
        A1[i] = f2bf(w1[(co * CIN + ci) * 9 + tap]);
    } else {
        int t = i - 221184;
        if (t < 98304) {
            int j = t & 7, l = (t >> 3) & 63, cf = (t >> 9) & 7, r = t >> 12; // r 0..23
            int ks = r & 3, m = r >> 2;
            int co = cf * 16 + (l & 15);
            int ci = ks * 32 + 8 * (l >> 4) + j;
            A2[t] = f2bf(coef[co * KF + ci * 6 + m]);
        }
    }
}

// ---------------------------------------------------------------------------
// conv1 via MFMA: tile 16x8 px, M=128 co, K = 9 taps x 6 ci-chunks of 32.
// LDS: input halo tile 10 rows x 18 cols, bf16, [col=r'*18+x'][ci], CST=200.
#define CST 200
__global__ __launch_bounds__(256) void k_conv1m(const float* __restrict__ feat,
                                                const float* __restrict__ wgt,
                                                const ushort* __restrict__ A1,
                                                const float* __restrict__ b1,
                                                float* __restrict__ hmid) {
    const int w0 = blockIdx.x * 16, h0 = blockIdx.y * 8, n = blockIdx.z;
    __shared__ ushort sIn[180 * CST];   // 72000 B
    const int tid = threadIdx.x;

    // ---- staging: in[ci][h0-1+r'][w0-1+x'] -> sIn[(r'*18+x')*CST + ci]
    {   // main: x' = tid&15, row_id = (tid>>4) + it*16 over 1920 (ci,r') rows
        int xl = tid & 15;
        int gw = w0 - 1 + xl;
        bool vw = (unsigned)gw < 96u;
        int rid = tid >> 4;
        int ci = rid / 10, rp = rid - ci * 10;
        for (int it = 0; it < 120; ++it) {
            int gh = h0 - 1 + rp;
            float v = 0.f;
            if (vw && (unsigned)gh < 96u)
                v = (ci < CC) ? feat[((n * CC + ci) * HH + gh) * WW_ + gw]
                              : wgt[((n * CWW + ci - CC) * HH + gh) * WW_ + gw];
            sIn[(rp * 18 + xl) * CST + ci] = f2bf(v);
            ci += 1; rp += 6; if (rp >= 10) { rp -= 10; ci += 1; }
        }
    }
    {   // edge: x' = 16 + (tid&1), row_id = (tid>>1) + it*128
        int xl = 16 + (tid & 1);
        int gw = w0 - 1 + xl;
        bool vw = (unsigned)gw < 96u;
        int rid = tid >> 1;
        int ci = rid / 10, rp = rid - ci * 10;
        for (int it = 0; it < 15; ++it) {
            int gh = h0 - 1 + rp;
            float v = 0.f;
            if (vw && (unsigned)gh < 96u)
                v = (ci < CC) ? feat[((n * CC + ci) * HH + gh) * WW_ + gw]
                              : wgt[((n * CWW + ci - CC) * HH + gh) * WW_ + gw];
            sIn[(rp * 18 + xl) * CST + ci] = f2bf(v);
            ci += 12; rp += 8; if (rp >= 10) { rp -= 10; ci += 1; }
        }
    }
    __syncthreads();

    // ---- MFMA main loop
    const int l = tid & 63, wv = tid >> 6;      // 4 waves, wave owns rows lr = wv*2 + nf
    const int lx = l & 15, cg = l >> 4;
    f32x4 z = {0.f, 0.f, 0.f, 0.f};
    f32x4 acc[8][2];
#pragma unroll
    for (int mf = 0; mf < 8; ++mf) { acc[mf][0] = z; acc[mf][1] = z; }

    const bf16x8* Ap = (const bf16x8*)A1 + l;
    int ks = 0;
#pragma unroll
    for (int tap = 0; tap < 9; ++tap) {
        const int dy = tap / 3, dx = tap % 3;
        const int col0 = (wv * 2 + dy) * 18 + lx + dx;
#pragma unroll
        for (int kc = 0; kc < 6; ++kc, ++ks) {
            const int ko = kc * 32 + 8 * cg;
            bf16x8 bfr0 = *(const bf16x8*)&sIn[col0 * CST + ko];
            bf16x8 bfr1 = *(const bf16x8*)&sIn[(col0 + 18) * CST + ko];
#pragma unroll
            for (int mf = 0; mf < 8; ++mf) {
                bf16x8 a = Ap[(ks * 8 + mf) * 64];
                acc[mf][0] = __builtin_amdgcn_mfma_f32_16x16x32_bf16(a, bfr0, acc[mf][0], 0, 0, 0);
                acc[mf][1] = __builtin_amdgcn_mfma_f32_16x16x32_bf16(a, bfr1, acc[mf][1], 0, 0, 0);
            }
        }
    }

    // ---- epilogue: bias + tanh, store. D: col(px)=l&15, row(co)=cg*4+reg
#pragma unroll
    for (int mf = 0; mf < 8; ++mf)
#pragma unroll
        for (int nf = 0; nf < 2; ++nf) {
            const int h = h0 + wv * 2 + nf;
#pragma unroll
            for (int r = 0; r < 4; ++r) {
                int co = mf * 16 + cg * 4 + r;
                float x = acc[mf][nf][r] + b1[co];
                hmid[((n * CC + co) * HH + h) * WW_ + w0 + lx] = fast_tanh(x);
            }
        }
}

// ---------------------------------------------------------------------------
// conv2 (1x1, 128->36) + tanh + basis mix (36 -> 54).  (fp32, unchanged)
__global__ __launch_bounds__(256) void k_conv2(const float* __restrict__ hmid,
                                               const float* __restrict__ w2,
                                               const float* __restrict__ b2,
                                               const float* __restrict__ bbuf,
                                               float* __restrict__ bases) {
    __shared__ float sW2[B36 * CC];
    __shared__ float sBB[TEM * 9];
    for (int i = threadIdx.x; i < B36 * CC; i += 256) sW2[i] = w2[i];
    if (threadIdx.x < TEM * 9) sBB[threadIdx.x] = bbuf[threadIdx.x];
    __syncthreads();

    const int n   = blockIdx.y;
    const int pix = blockIdx.x * 256 + threadIdx.x;

    float a[B36];
#pragma unroll
    for (int k = 0; k < B36; ++k) a[k] = b2[k];

    const float* hp = &hmid[(size_t)(n * CC) * HW + pix];
    for (int c = 0; c < CC; ++c) {
        float hv = hp[c * HW];
#pragma unroll
        for (int k = 0; k < B36; ++k) a[k] = fmaf(hv, sW2[k * CC + c], a[k]);
    }
#pragma unroll
    for (int k = 0; k < B36; ++k) a[k] = fast_tanh(a[k]);

    float* bp = &bases[(size_t)(n * 54) * HW + pix];
#pragma unroll
    for (int m = 0; m < NB; ++m) {
#pragma unroll
        for (int ll = 0; ll < 9; ++ll) {
            float s = 0.f;
#pragma unroll
            for (int t = 0; t < TEM; ++t) s = fmaf(a[m * TEM + t], sBB[t * 9 + ll], s);
            bp[(m * 9 + ll) * HW] = s;
        }
    }
}

// ---------------------------------------------------------------------------
// F GEMM via MFMA: F[m][px][co] = sum_ci coef[co][ci*6+m] * feat[n][ci][px]
// A-operand = feat (M=px), B-operand = coef (N=co). 256-px tiles, 8 waves.
#define CST2 136
__global__ __launch_bounds__(512) void k_fm_m(const float* __restrict__ feat,
                                              const ushort* __restrict__ A2,
                                              float* __restrict__ F,
                                              int n_base, int batched) {
    const int n = n_base + blockIdx.y;
    const int px0 = blockIdx.x * 256;
    float* Fp = F + (batched ? (size_t)n * FSTRIDE : 0);
    __shared__ ushort sF[256 * CST2];   // 69632 B
    const int tid = threadIdx.x;

    // staging: pairs (ci, ci+1) per lane, px across lanes (coalesced)
    for (int it = 0; it < 32; ++it) {
        int i = it * 512 + tid;         // 16384 pairs
        int px = i & 255;
        int ci = (i >> 8) * 2;
        const float* fp = &feat[((size_t)(n * CC + ci)) * HW + px0 + px];
        unsigned lo = f2bf(fp[0]);
        unsigned hi = f2bf(fp[HW]);
        *(unsigned*)&sF[px * CST2 + ci] = lo | (hi << 16);
    }
    __syncthreads();

    const int l = tid & 63, wv = tid >> 6;   // 8 waves x 32 px
    const int lx = l & 15, cg = l >> 4;
    f32x4 z = {0.f, 0.f, 0.f, 0.f};
    const bf16x8* Bp = (const bf16x8*)A2 + l;

    for (int m = 0; m < 6; ++m) {
        f32x4 acc[8][2];
#pragma unroll
        for (int cf = 0; cf < 8; ++cf) { acc[cf][0] = z; acc[cf][1] = z; }
#pragma unroll
        for (int ksi = 0; ksi < 4; ++ksi) {
            const int col0 = wv * 32 + lx;
            const int ko = ksi * 32 + 8 * cg;
            bf16x8 a0 = *(const bf16x8*)&sF[col0 * CST2 + ko];
            bf16x8 a1 = *(const bf16x8*)&sF[(col0 + 16) * CST2 + ko];
#pragma unroll
            for (int cf = 0; cf < 8; ++cf) {
                bf16x8 b = Bp[((m * 4 + ksi) * 8 + cf) * 64];
                acc[cf][0] = __builtin_amdgcn_mfma_f32_16x16x32_bf16(a0, b, acc[cf][0], 0, 0, 0);
                acc[cf][1] = __builtin_amdgcn_mfma_f32_16x16x32_bf16(a1, b, acc[cf][1], 0, 0, 0);
            }
        }
        // D: col(co) = cf*16+lx, row(px) = strip + nf*16 + cg*4 + r
#pragma unroll
        for (int cf = 0; cf < 8; ++cf)
#pragma unroll
            for (int nf = 0; nf < 2; ++nf)
#pragma unroll
                for (int r = 0; r < 4; ++r) {
                    int px = wv * 32 + nf * 16 + cg * 4 + r;
                    Fp[((size_t)m * HW + px0 + px) * CC + cf * 16 + lx] = acc[cf][nf][r];
                }
    }
}

// ---------------------------------------------------------------------------
// Combine: out[co,h,w] = bias[co] + sum_{m,dy,dx} bases[m,dy*3+dx,h,w]*F[m,h+dy-1,w+dx-1,co]
__global__ __launch_bounds__(256) void k_comb(const float* __restrict__ F,
                                              const float* __restrict__ bases,
                                              const float* __restrict__ bias,
                                              float* __restrict__ out,
                                              int n_base, int batched) {
    const int wt = blockIdx.x, h = blockIdx.y;
    const int n = n_base + (blockIdx.z >> 1);
    const int coz = blockIdx.z & 1;
    const float* Fp = F + (batched ? (size_t)n * FSTRIDE : 0);
    const int w0 = wt * 32;
    __shared__ float sBa[54][32];
    __shared__ float sOut[64][33];

    for (int i = threadIdx.x; i < 54 * 32; i += 256) {
        int j = i >> 5, p = i & 31;
        sBa[j][p] = bases[((size_t)(n * 54 + j)) * HW + h * WW_ + w0 + p];
    }
    __syncthreads();

    const int col = threadIdx.x & 63;
    const int co  = coz * 64 + col;
    const int q   = threadIdx.x >> 6;
    const int pxb = q * 8;

    float acc[8];
    const float bv = bias[co];
#pragma unroll
    for (int p = 0; p < 8; ++p) acc[p] = bv;

#pragma unroll
    for (int m = 0; m < NB; ++m) {
#pragma unroll
        for (int dy = 0; dy < 3; ++dy) {
            const int hh2 = h - 1 + dy;
            float rr[10];
            if ((unsigned)hh2 < HH) {
#pragma unroll
                for (int x = 0; x < 10; ++x) {
                    int c2 = w0 + pxb - 1 + x;
                    rr[x] = ((unsigned)c2 < WW_)
                          ? Fp[(((size_t)(m * HH + hh2)) * WW_ + c2) * CC + co] : 0.f;
                }
            } else {
#pragma unroll
                for (int x = 0; x < 10; ++x) rr[x] = 0.f;
            }
#pragma unroll
            for (int dx = 0; dx < 3; ++dx) {
                const float* sb = &sBa[m * 9 + dy * 3 + dx][pxb];
#pragma unroll
                for (int p = 0; p < 8; ++p)
                    acc[p] = fmaf(sb[p], rr[p + dx], acc[p]);
            }
        }
    }

#pragma unroll
    for (int p = 0; p < 8; ++p) sOut[col][pxb + p] = acc[p];
    __syncthreads();

    const int sc = threadIdx.x & 31;
#pragma unroll
    for (int it = 0; it < 8; ++it) {
        int row = (threadIdx.x >> 5) + it * 8;
        out[((size_t)(n * CC + coz * 64 + row)) * HW + h * WW_ + w0 + sc] = sOut[row][sc];
    }
}

// ---------------------------------------------------------------------------
extern "C" void kernel_launch(void* const* d_in, const int* in_sizes, int n_in,
                              void* d_out, int out_size, void* d_ws, size_t ws_size,
                              hipStream_t stream) {
    const float* feat = (const float*)d_in[0];
    const float* wgt  = (const float*)d_in[1];
    const float* w1   = (const float*)d_in[2];
    const float* b1   = (const float*)d_in[3];
    const float* w2   = (const float*)d_in[4];
    const float* b2   = (const float*)d_in[5];
    const float* bbuf = (const float*)d_in[6];
    const float* coef = (const float*)d_in[7];
    const float* bias = (const float*)d_in[8];
    float* out = (float*)d_out;

    float* ws = (float*)d_ws;
    ushort* A1   = (ushort*)(ws + OFF_A1);
    ushort* A2   = (ushort*)(ws + OFF_A2);
    float* bases = ws + OFF_BASES;
    float* hmid  = ws + OFF_HMID;
    float* F     = ws + OFF_HMID;   // F reuses hmid region (dead after conv2)

    const bool batched = ws_size >= (size_t)60764160 * 4;

    k_prep  <<<dim3(1248),       dim3(256), 0, stream>>>(w1, coef, A1, A2);
    k_conv1m<<<dim3(6, 12, NN),  dim3(256), 0, stream>>>(feat, wgt, A1, b1, hmid);
    k_conv2 <<<dim3(36, NN),     dim3(256), 0, stream>>>(hmid, w2, b2, bbuf, bases);

    if (batched) {
        k_fm_m<<<dim3(36, NN),    dim3(512), 0, stream>>>(feat, A2, F, 0, 1);
        k_comb<<<dim3(3, HH, 2 * NN), dim3(256), 0, stream>>>(F, bases, bias, out, 0, 1);
    } else {
        for (int n = 0; n < NN; ++n) {
            k_fm_m<<<dim3(36, 1), dim3(512), 0, stream>>>(feat, A2, F, n, 0);
            k_comb<<<dim3(3, HH, 2), dim3(256), 0, stream>>>(F, bases, bias, out, n, 0);
        }
    }
}

// Round 4
// 605.793 us; speedup vs baseline: 2.7589x; 1.6983x over previous
//
#include <hip/hip_runtime.h>

// Problem constants
#define NN   8
#define CC   128
#define CWW  64
#define CIN  192
#define HH   96
#define WW_  96
#define HW   (HH*WW_)      // 9216
#define NB   6
#define TEM  6
#define B36  36
#define KF   768

typedef __attribute__((ext_vector_type(8))) short bf16x8;
typedef __attribute__((ext_vector_type(4))) float f32x4;

// workspace layout (float offsets)
#define OFF_A1     0           // 221184 ushorts = 110592 floats
#define OFF_A2     110592      // 98304 ushorts = 49152 floats
#define OFF_BASES  159744      // 8*54*9216 = 3981312 floats
#define OFF_HMID   4141056     // 8*128*9216 ushorts = 4718592 floats
// total floats used = 8859648 (~33.8 MiB)

__device__ inline ushort f2bf(float f) {
    union { float f; unsigned u; } x; x.f = f;
    unsigned r = x.u + 0x7FFFu + ((x.u >> 16) & 1u);
    return (ushort)(r >> 16);
}
__device__ inline float bf2f(ushort h) {
    union { unsigned u; float f; } t; t.u = ((unsigned)h) << 16; return t.f;
}
__device__ inline float fast_tanh(float x) {
    x = fminf(fmaxf(x, -15.f), 15.f);
    float e = __expf(2.f * x);
    float r;
    asm volatile("v_rcp_f32 %0, %1" : "=v"(r) : "v"(e + 1.f));
    return (e - 1.f) * r;
}

// ---------------------------------------------------------------------------
// Prep: pack conv1 weights and coef into MFMA fragment order (bf16).
__global__ __launch_bounds__(256) void k_prep(const float* __restrict__ w1,
                                              const float* __restrict__ coef,
                                              ushort* __restrict__ A1,
                                              ushort* __restrict__ A2) {
    int i = blockIdx.x * 256 + threadIdx.x;
    if (i < 221184) {
        int j = i & 7, l = (i >> 3) & 63, mf = (i >> 9) & 7, ks = i >> 12; // ks 0..53
        int kc = ks % 6, tap = ks / 6;
        int co = mf * 16 + (l & 15);
        int ci = kc * 32 + 8 * (l >> 4) + j;
        A1[i] = f2bf(w1[(co * CIN + ci) * 9 + tap]);
    } else {
        int t = i - 221184;
        if (t < 98304) {
            int j = t & 7, l = (t >> 3) & 63, cf = (t >> 9) & 7, r = t >> 12; // r 0..23
            int ks = r & 3, m = r >> 2;
            int co = cf * 16 + (l & 15);
            int ci = ks * 32 + 8 * (l >> 4) + j;
            A2[t] = f2bf(coef[co * KF + ci * 6 + m]);
        }
    }
}

// ---------------------------------------------------------------------------
// conv1 via MFMA (unchanged except bf16 hmid output).
#define CST 200
__global__ __launch_bounds__(256) void k_conv1m(const float* __restrict__ feat,
                                                const float* __restrict__ wgt,
                                                const ushort* __restrict__ A1,
                                                const float* __restrict__ b1,
                                                ushort* __restrict__ hmid) {
    const int w0 = blockIdx.x * 16, h0 = blockIdx.y * 8, n = blockIdx.z;
    __shared__ ushort sIn[180 * CST];
    const int tid = threadIdx.x;

    {   // main staging
        int xl = tid & 15;
        int gw = w0 - 1 + xl;
        bool vw = (unsigned)gw < 96u;
        int rid = tid >> 4;
        int ci = rid / 10, rp = rid - ci * 10;
        for (int it = 0; it < 120; ++it) {
            int gh = h0 - 1 + rp;
            float v = 0.f;
            if (vw && (unsigned)gh < 96u)
                v = (ci < CC) ? feat[((n * CC + ci) * HH + gh) * WW_ + gw]
                              : wgt[((n * CWW + ci - CC) * HH + gh) * WW_ + gw];
            sIn[(rp * 18 + xl) * CST + ci] = f2bf(v);
            ci += 1; rp += 6; if (rp >= 10) { rp -= 10; ci += 1; }
        }
    }
    {   // edge staging
        int xl = 16 + (tid & 1);
        int gw = w0 - 1 + xl;
        bool vw = (unsigned)gw < 96u;
        int rid = tid >> 1;
        int ci = rid / 10, rp = rid - ci * 10;
        for (int it = 0; it < 15; ++it) {
            int gh = h0 - 1 + rp;
            float v = 0.f;
            if (vw && (unsigned)gh < 96u)
                v = (ci < CC) ? feat[((n * CC + ci) * HH + gh) * WW_ + gw]
                              : wgt[((n * CWW + ci - CC) * HH + gh) * WW_ + gw];
            sIn[(rp * 18 + xl) * CST + ci] = f2bf(v);
            ci += 12; rp += 8; if (rp >= 10) { rp -= 10; ci += 1; }
        }
    }
    __syncthreads();

    const int l = tid & 63, wv = tid >> 6;
    const int lx = l & 15, cg = l >> 4;
    f32x4 z = {0.f, 0.f, 0.f, 0.f};
    f32x4 acc[8][2];
#pragma unroll
    for (int mf = 0; mf < 8; ++mf) { acc[mf][0] = z; acc[mf][1] = z; }

    const bf16x8* Ap = (const bf16x8*)A1 + l;
    int ks = 0;
#pragma unroll
    for (int tap = 0; tap < 9; ++tap) {
        const int dy = tap / 3, dx = tap % 3;
        const int col0 = (wv * 2 + dy) * 18 + lx + dx;
#pragma unroll
        for (int kc = 0; kc < 6; ++kc, ++ks) {
            const int ko = kc * 32 + 8 * cg;
            bf16x8 bfr0 = *(const bf16x8*)&sIn[col0 * CST + ko];
            bf16x8 bfr1 = *(const bf16x8*)&sIn[(col0 + 18) * CST + ko];
#pragma unroll
            for (int mf = 0; mf < 8; ++mf) {
                bf16x8 a = Ap[(ks * 8 + mf) * 64];
                acc[mf][0] = __builtin_amdgcn_mfma_f32_16x16x32_bf16(a, bfr0, acc[mf][0], 0, 0, 0);
                acc[mf][1] = __builtin_amdgcn_mfma_f32_16x16x32_bf16(a, bfr1, acc[mf][1], 0, 0, 0);
            }
        }
    }

#pragma unroll
    for (int mf = 0; mf < 8; ++mf)
#pragma unroll
        for (int nf = 0; nf < 2; ++nf) {
            const int h = h0 + wv * 2 + nf;
#pragma unroll
            for (int r = 0; r < 4; ++r) {
                int co = mf * 16 + cg * 4 + r;
                float x = acc[mf][nf][r] + b1[co];
                hmid[((n * CC + co) * HH + h) * WW_ + w0 + lx] = f2bf(fast_tanh(x));
            }
        }
}

// ---------------------------------------------------------------------------
// conv2 (1x1, 128->36) + tanh + basis mix (36 -> 54). hmid now bf16.
__global__ __launch_bounds__(256) void k_conv2(const ushort* __restrict__ hmid,
                                               const float* __restrict__ w2,
                                               const float* __restrict__ b2,
                                               const float* __restrict__ bbuf,
                                               float* __restrict__ bases) {
    __shared__ float sW2[B36 * CC];
    __shared__ float sBB[TEM * 9];
    for (int i = threadIdx.x; i < B36 * CC; i += 256) sW2[i] = w2[i];
    if (threadIdx.x < TEM * 9) sBB[threadIdx.x] = bbuf[threadIdx.x];
    __syncthreads();

    const int n   = blockIdx.y;
    const int pix = blockIdx.x * 256 + threadIdx.x;

    float a[B36];
#pragma unroll
    for (int k = 0; k < B36; ++k) a[k] = b2[k];

    const ushort* hp = &hmid[(size_t)(n * CC) * HW + pix];
    for (int c = 0; c < CC; ++c) {
        float hv = bf2f(hp[c * HW]);
#pragma unroll
        for (int k = 0; k < B36; ++k) a[k] = fmaf(hv, sW2[k * CC + c], a[k]);
    }
#pragma unroll
    for (int k = 0; k < B36; ++k) a[k] = fast_tanh(a[k]);

    float* bp = &bases[(size_t)(n * 54) * HW + pix];
#pragma unroll
    for (int m = 0; m < NB; ++m) {
#pragma unroll
        for (int ll = 0; ll < 9; ++ll) {
            float s = 0.f;
#pragma unroll
            for (int t = 0; t < TEM; ++t) s = fmaf(a[m * TEM + t], sBB[t * 9 + ll], s);
            bp[(m * 9 + ll) * HW] = s;
        }
    }
}

// ---------------------------------------------------------------------------
// Fused F-GEMM + dynamic combine. Block: 32x3 out px (halo 34x5=170), 128 co.
// 512 thr = 8 waves: MFMA waves (mg in {0,1} x 4 co-frags, ng in {0..3} px-tiles).
// sFeat: bf16 [px][128ci], 16B-group XOR swizzle (g^px&15) -> conflict-free b128.
// sFm: bf16 [px][co], stride 134.
#define FMT 134
__global__ __launch_bounds__(512) void k_fused(const float* __restrict__ feat,
                                               const ushort* __restrict__ A2,
                                               const float* __restrict__ bases,
                                               const float* __restrict__ bias,
                                               float* __restrict__ out) {
    const int wt = blockIdx.x, ht = blockIdx.y, n = blockIdx.z;
    const int w0 = wt * 32, h0 = ht * 3;
    __shared__ ushort sFeat[176 * 128];     // 45 KB
    __shared__ ushort sFm[176 * FMT];       // 46.1 KB
    __shared__ float  sBa[54 * 96];         // 20.25 KB
    const int tid = threadIdx.x;

    // ---- stage feat halo (170 px x 64 ci-pairs), XOR-swizzled bf16
    for (int it = 0; it < 22; ++it) {
        int i = it * 512 + tid;
        if (i < 170 * 64) {
            int hp = i % 170;
            int cp = (i / 170) * 2;
            int hy2 = hp / 34, hx2 = hp - hy2 * 34;
            int gh = h0 - 1 + hy2, gw = w0 - 1 + hx2;
            unsigned v = 0u;
            if ((unsigned)gh < 96u && (unsigned)gw < 96u) {
                const float* fp = &feat[((size_t)(n * CC + cp)) * HW + gh * WW_ + gw];
                v = (unsigned)f2bf(fp[0]) | ((unsigned)f2bf(fp[HW]) << 16);
            }
            int idx = hp * 128 + (((cp >> 3) ^ (hp & 15)) << 3) + (cp & 7);
            *(unsigned*)&sFeat[idx] = v;
        }
    }
    // zero pad rows 170..175
    for (int j = tid; j < 6 * 64; j += 512) ((unsigned*)&sFeat[170 * 128])[j] = 0u;
    // stage bases tile (54 x 96 fp32)
    for (int it = 0; it < 11; ++it) {
        int i = it * 512 + tid;
        if (i < 54 * 96) {
            int j = i / 96, p = i - j * 96;
            int hy = p >> 5, wx = p & 31;
            sBa[i] = bases[((size_t)(n * 54 + j)) * HW + (h0 + hy) * WW_ + w0 + wx];
        }
    }
    __syncthreads();

    const int l  = tid & 63, wv = tid >> 6;
    const int lx = l & 15, cg = l >> 4;
    const int mg = wv & 1, ng = wv >> 1;
    const int nt = (ng == 3) ? 2 : 3;        // tiles 9,10 only for ng=3 (11 tiles cover 176 px)
    const int co_l = tid & 127;              // combine: lane owns one co
    const int g4   = tid >> 7;               // combine: px-group -> wx0 = g4*8
    const int wx0  = g4 * 8;

    float accO[3][8];
#pragma unroll
    for (int a = 0; a < 3; ++a)
#pragma unroll
        for (int p = 0; p < 8; ++p) accO[a][p] = 0.f;

    const bf16x8* Ap = (const bf16x8*)A2;
    const f32x4 z = {0.f, 0.f, 0.f, 0.f};

    for (int m = 0; m < 6; ++m) {
        __syncthreads();        // sFm free (previous combine done)

        // ---- MFMA: F_m[co][px] over the halo tile
        f32x4 acc[4][3];
#pragma unroll
        for (int mi = 0; mi < 4; ++mi)
#pragma unroll
            for (int ti = 0; ti < 3; ++ti) acc[mi][ti] = z;

#pragma unroll
        for (int ks = 0; ks < 4; ++ks) {
            bf16x8 a[4];
#pragma unroll
            for (int mi = 0; mi < 4; ++mi)
                a[mi] = Ap[((size_t)((m * 4 + ks) * 8 + mg * 4 + mi)) * 64 + l];
            const int gsw = (ks * 4 + cg) ^ lx;
#pragma unroll
            for (int ti = 0; ti < 3; ++ti) {
                if (ti < nt) {
                    int px = (ng * 3 + ti) * 16 + lx;
                    bf16x8 b = *(const bf16x8*)&sFeat[px * 128 + (gsw << 3)];
#pragma unroll
                    for (int mi = 0; mi < 4; ++mi)
                        acc[mi][ti] = __builtin_amdgcn_mfma_f32_16x16x32_bf16(a[mi], b, acc[mi][ti], 0, 0, 0);
                }
            }
        }
        // write F_m -> sFm (bf16). D: col(px)=lx, row(co)=cg*4+r
#pragma unroll
        for (int ti = 0; ti < 3; ++ti) {
            if (ti < nt) {
                int px = (ng * 3 + ti) * 16 + lx;
#pragma unroll
                for (int mi = 0; mi < 4; ++mi) {
                    int co = (mg * 4 + mi) * 16 + cg * 4;
                    unsigned v0 = (unsigned)f2bf(acc[mi][ti][0]) | ((unsigned)f2bf(acc[mi][ti][1]) << 16);
                    unsigned v1 = (unsigned)f2bf(acc[mi][ti][2]) | ((unsigned)f2bf(acc[mi][ti][3]) << 16);
                    *(unsigned*)&sFm[px * FMT + co]     = v0;
                    *(unsigned*)&sFm[px * FMT + co + 2] = v1;
                }
            }
        }
        __syncthreads();        // F_m ready

        // ---- combine partial: accO += sum_tau bases[m,tau]*F_m(shifted)
#pragma unroll
        for (int hy = 0; hy < 3; ++hy) {
#pragma unroll
            for (int dy = 0; dy < 3; ++dy) {
                const int hrow = (hy + dy) * 34 + wx0;
                float rr[10];
#pragma unroll
                for (int x = 0; x < 10; ++x)
                    rr[x] = bf2f(sFm[(hrow + x) * FMT + co_l]);
#pragma unroll
                for (int dx = 0; dx < 3; ++dx) {
                    const float* sb = &sBa[(m * 9 + dy * 3 + dx) * 96 + hy * 32 + wx0];
#pragma unroll
                    for (int p = 0; p < 8; ++p)
                        accO[hy][p] = fmaf(sb[p], rr[p + dx], accO[hy][p]);
                }
            }
        }
    }

    // ---- epilogue: bias + store
    const float bv = bias[co_l];
#pragma unroll
    for (int hy = 0; hy < 3; ++hy) {
        float4 o0, o1;
        o0.x = accO[hy][0] + bv; o0.y = accO[hy][1] + bv;
        o0.z = accO[hy][2] + bv; o0.w = accO[hy][3] + bv;
        o1.x = accO[hy][4] + bv; o1.y = accO[hy][5] + bv;
        o1.z = accO[hy][6] + bv; o1.w = accO[hy][7] + bv;
        float* op = &out[((size_t)(n * CC + co_l)) * HW + (h0 + hy) * WW_ + w0 + wx0];
        *(float4*)op       = o0;
        *(float4*)(op + 4) = o1;
    }
}

// ---------------------------------------------------------------------------
extern "C" void kernel_launch(void* const* d_in, const int* in_sizes, int n_in,
                              void* d_out, int out_size, void* d_ws, size_t ws_size,
                              hipStream_t stream) {
    const float* feat = (const float*)d_in[0];
    const float* wgt  = (const float*)d_in[1];
    const float* w1   = (const float*)d_in[2];
    const float* b1   = (const float*)d_in[3];
    const float* w2   = (const float*)d_in[4];
    const float* b2   = (const float*)d_in[5];
    const float* bbuf = (const float*)d_in[6];
    const float* coef = (const float*)d_in[7];
    const float* bias = (const float*)d_in[8];
    float* out = (float*)d_out;

    float* ws = (float*)d_ws;
    ushort* A1   = (ushort*)(ws + OFF_A1);
    ushort* A2   = (ushort*)(ws + OFF_A2);
    float* bases = ws + OFF_BASES;
    ushort* hmid = (ushort*)(ws + OFF_HMID);

    k_prep  <<<dim3(1248),      dim3(256), 0, stream>>>(w1, coef, A1, A2);
    k_conv1m<<<dim3(6, 12, NN), dim3(256), 0, stream>>>(feat, wgt, A1, b1, hmid);
    k_conv2 <<<dim3(36, NN),    dim3(256), 0, stream>>>(hmid, w2, b2, bbuf, bases);
    k_fused <<<dim3(3, 32, NN), dim3(512), 0, stream>>>(feat, A2, bases, bias, out);
}

// Round 5
// 361.016 us; speedup vs baseline: 4.6295x; 1.6780x over previous
//
#include <hip/hip_runtime.h>

// Problem constants
#define NN   8
#define CC   128
#define CWW  64
#define CIN  192
#define HH   96
#define WW_  96
#define HW   (HH*WW_)      // 9216
#define NB   6
#define TEM  6
#define B36  36
#define KF   768

typedef __attribute__((ext_vector_type(8))) short bf16x8;
typedef __attribute__((ext_vector_type(4))) float f32x4;

// workspace layout (float offsets)
#define OFF_A1     0           // 221184 ushorts = 110592 floats
#define OFF_A2     110592      // 98304 ushorts = 49152 floats
#define OFF_BASES  159744      // 8*54*9216 = 3981312 floats
#define OFF_HMID   4141056     // 8*128*9216 ushorts = 4718592 floats

__device__ inline ushort f2bf(float f) {
    union { float f; unsigned u; } x; x.f = f;
    unsigned r = x.u + 0x7FFFu + ((x.u >> 16) & 1u);
    return (ushort)(r >> 16);
}
__device__ inline float bf2f(ushort h) {
    union { unsigned u; float f; } t; t.u = ((unsigned)h) << 16; return t.f;
}
__device__ inline float fast_tanh(float x) {
    x = fminf(fmaxf(x, -15.f), 15.f);
    float e = __expf(2.f * x);
    float r;
    asm volatile("v_rcp_f32 %0, %1" : "=v"(r) : "v"(e + 1.f));
    return (e - 1.f) * r;
}

// ---------------------------------------------------------------------------
// Prep: pack conv1 weights and coef into MFMA fragment order (bf16).
// conv1 K-order is now kc-major: ks = kc*9 + tap.
__global__ __launch_bounds__(256) void k_prep(const float* __restrict__ w1,
                                              const float* __restrict__ coef,
                                              ushort* __restrict__ A1,
                                              ushort* __restrict__ A2) {
    int i = blockIdx.x * 256 + threadIdx.x;
    if (i < 221184) {
        int j = i & 7, l = (i >> 3) & 63, mf = (i >> 9) & 7, ks = i >> 12; // ks 0..53
        int kc = ks / 9, tap = ks - kc * 9;
        int co = mf * 16 + (l & 15);
        int ci = kc * 32 + 8 * (l >> 4) + j;
        A1[i] = f2bf(w1[(co * CIN + ci) * 9 + tap]);
    } else {
        int t = i - 221184;
        if (t < 98304) {
            int j = t & 7, l = (t >> 3) & 63, cf = (t >> 9) & 7, r = t >> 12; // r 0..23
            int ks = r & 3, m = r >> 2;
            int co = cf * 16 + (l & 15);
            int ci = ks * 32 + 8 * (l >> 4) + j;
            A2[t] = f2bf(coef[co * KF + ci * 6 + m]);
        }
    }
}

// ---------------------------------------------------------------------------
// conv1 via MFMA, v2: 16x16 px tile, 4 waves (each owns 4 px rows),
// A (weights) double-buffered through LDS (8 KB/K-step, T14 split),
// B (input halo) staged per-kc slice (18x18 cols x 32 ci), double-buffered,
// prefetch spread over taps 0..6 (3 slots/tap, T14 split).
#define SBS 40   // ushorts per halo col (32 ci + pad, 16B-aligned stride)
__global__ __launch_bounds__(256, 2) void k_conv1m(const float* __restrict__ feat,
                                                   const float* __restrict__ wgt,
                                                   const ushort* __restrict__ A1,
                                                   const float* __restrict__ b1,
                                                   ushort* __restrict__ hmid) {
    const int w0 = blockIdx.x * 16, h0 = blockIdx.y * 16, n = blockIdx.z;
    __shared__ ushort sB[2][324 * SBS];   // 2 x 25.9 KB
    __shared__ ushort sA[2][4096];        // 2 x 8 KB
    const int tid = threadIdx.x;
    const int l = tid & 63, wv = tid >> 6, lx = l & 15, cg = l >> 4;

    f32x4 acc[8][4];
    const f32x4 z = {0.f, 0.f, 0.f, 0.f};
#pragma unroll
    for (int mf = 0; mf < 8; ++mf)
#pragma unroll
        for (int nf = 0; nf < 4; ++nf) acc[mf][nf] = z;

    // ---- prologue: B slice kc=0 (inline), A slice ks=0
#pragma unroll 1
    for (int it = 0; it < 21; ++it) {
        int i = it * 256 + tid;
        if (i < 5184) {
            int cpair = i / 324, col = i - cpair * 324;
            int rp = col / 18, xl = col - rp * 18;
            int gh = h0 - 1 + rp, gw = w0 - 1 + xl;
            int cp = cpair * 2;                       // kc=0 -> ci = cp (feat)
            unsigned v = 0u;
            if ((unsigned)gh < 96u && (unsigned)gw < 96u) {
                const float* fp = &feat[((size_t)(n * CC + cp)) * HW + gh * WW_ + gw];
                v = (unsigned)f2bf(fp[0]) | ((unsigned)f2bf(fp[HW]) << 16);
            }
            *(unsigned*)&sB[0][col * SBS + cp] = v;
        }
    }
    {
        const uint4* src = (const uint4*)A1;
        uint4 v0 = src[tid], v1 = src[256 + tid];
        ((uint4*)&sA[0][0])[tid] = v0;
        ((uint4*)&sA[0][0])[256 + tid] = v1;
    }
    __syncthreads();

    // ---- main loop: kc-major K
#pragma unroll 1
    for (int kc = 0; kc < 6; ++kc) {
#pragma unroll 1
        for (int tap = 0; tap < 9; ++tap) {
            const int ks = kc * 9 + tap;
            const int ab = ks & 1, bb = kc & 1;

            // A prefetch: issue loads (write after MFMA)
            uint4 pA0, pA1;
            const bool doA = (ks < 53);
            if (doA) {
                const uint4* src = (const uint4*)(A1 + (size_t)(ks + 1) * 4096);
                pA0 = src[tid]; pA1 = src[256 + tid];
            }

            // B prefetch for kc+1: 3 slots this tap (taps 0..6 cover 21 slots)
            float pB0a = 0.f, pB0b = 0.f, pB1a = 0.f, pB1b = 0.f, pB2a = 0.f, pB2b = 0.f;
            int bo0 = -1, bo1 = -1, bo2 = -1;
            const bool doB = (kc < 5) && (tap < 7);
            if (doB) {
                const int nkc = kc + 1;
#pragma unroll
                for (int it = 0; it < 3; ++it) {
                    int i = (tap * 3 + it) * 256 + tid;
                    if (i < 5184) {
                        int cpair = i / 324, col = i - cpair * 324;
                        int rp = col / 18, xl = col - rp * 18;
                        int gh = h0 - 1 + rp, gw = w0 - 1 + xl;
                        int cp = cpair * 2, ci = nkc * 32 + cp;
                        float va = 0.f, vb = 0.f;
                        if ((unsigned)gh < 96u && (unsigned)gw < 96u) {
                            const float* fp = (ci < CC)
                                ? &feat[((size_t)(n * CC + ci)) * HW + gh * WW_ + gw]
                                : &wgt[((size_t)(n * CWW + ci - CC)) * HW + gh * WW_ + gw];
                            va = fp[0]; vb = fp[HW];
                        }
                        int off = col * SBS + cp;
                        if (it == 0)      { pB0a = va; pB0b = vb; bo0 = off; }
                        else if (it == 1) { pB1a = va; pB1b = vb; bo1 = off; }
                        else              { pB2a = va; pB2b = vb; bo2 = off; }
                    }
                }
            }

            // fragment reads + MFMA
            bf16x8 afr[8];
#pragma unroll
            for (int mf = 0; mf < 8; ++mf)
                afr[mf] = *(const bf16x8*)&sA[ab][(mf * 64 + l) * 8];
            const int dy = tap / 3, dx = tap - dy * 3;
            bf16x8 bfr[4];
#pragma unroll
            for (int nf = 0; nf < 4; ++nf) {
                int col0 = (wv * 4 + nf + dy) * 18 + lx + dx;
                bfr[nf] = *(const bf16x8*)&sB[bb][col0 * SBS + 8 * cg];
            }
#pragma unroll
            for (int mf = 0; mf < 8; ++mf)
#pragma unroll
                for (int nf = 0; nf < 4; ++nf)
                    acc[mf][nf] = __builtin_amdgcn_mfma_f32_16x16x32_bf16(afr[mf], bfr[nf], acc[mf][nf], 0, 0, 0);

            // write-back prefetches (T14: after compute)
            if (doA) {
                uint4* d = (uint4*)&sA[ab ^ 1][0];
                d[tid] = pA0; d[256 + tid] = pA1;
            }
            if (doB) {
                ushort* nb = &sB[bb ^ 1][0];
                if (bo0 >= 0) *(unsigned*)&nb[bo0] = (unsigned)f2bf(pB0a) | ((unsigned)f2bf(pB0b) << 16);
                if (bo1 >= 0) *(unsigned*)&nb[bo1] = (unsigned)f2bf(pB1a) | ((unsigned)f2bf(pB1b) << 16);
                if (bo2 >= 0) *(unsigned*)&nb[bo2] = (unsigned)f2bf(pB2a) | ((unsigned)f2bf(pB2b) << 16);
            }
            __syncthreads();
        }
    }

    // ---- epilogue: bias + tanh, bf16 store. D: col(px)=lx, row(co)=cg*4+r
#pragma unroll
    for (int mf = 0; mf < 8; ++mf)
#pragma unroll
        for (int nf = 0; nf < 4; ++nf) {
            const int h = h0 + wv * 4 + nf;
#pragma unroll
            for (int r = 0; r < 4; ++r) {
                int co = mf * 16 + cg * 4 + r;
                float x = acc[mf][nf][r] + b1[co];
                hmid[((size_t)(n * CC + co) * HH + h) * WW_ + w0 + lx] = f2bf(fast_tanh(x));
            }
        }
}

// ---------------------------------------------------------------------------
// conv2 (1x1, 128->36) + tanh + basis mix (36 -> 54). hmid bf16. (unchanged)
__global__ __launch_bounds__(256) void k_conv2(const ushort* __restrict__ hmid,
                                               const float* __restrict__ w2,
                                               const float* __restrict__ b2,
                                               const float* __restrict__ bbuf,
                                               float* __restrict__ bases) {
    __shared__ float sW2[B36 * CC];
    __shared__ float sBB[TEM * 9];
    for (int i = threadIdx.x; i < B36 * CC; i += 256) sW2[i] = w2[i];
    if (threadIdx.x < TEM * 9) sBB[threadIdx.x] = bbuf[threadIdx.x];
    __syncthreads();

    const int n   = blockIdx.y;
    const int pix = blockIdx.x * 256 + threadIdx.x;

    float a[B36];
#pragma unroll
    for (int k = 0; k < B36; ++k) a[k] = b2[k];

    const ushort* hp = &hmid[(size_t)(n * CC) * HW + pix];
    for (int c = 0; c < CC; ++c) {
        float hv = bf2f(hp[c * HW]);
#pragma unroll
        for (int k = 0; k < B36; ++k) a[k] = fmaf(hv, sW2[k * CC + c], a[k]);
    }
#pragma unroll
    for (int k = 0; k < B36; ++k) a[k] = fast_tanh(a[k]);

    float* bp = &bases[(size_t)(n * 54) * HW + pix];
#pragma unroll
    for (int m = 0; m < NB; ++m) {
#pragma unroll
        for (int ll = 0; ll < 9; ++ll) {
            float s = 0.f;
#pragma unroll
            for (int t = 0; t < TEM; ++t) s = fmaf(a[m * TEM + t], sBB[t * 9 + ll], s);
            bp[(m * 9 + ll) * HW] = s;
        }
    }
}

// ---------------------------------------------------------------------------
// Fused F-GEMM + dynamic combine. (unchanged from R3)
#define FMT 134
__global__ __launch_bounds__(512) void k_fused(const float* __restrict__ feat,
                                               const ushort* __restrict__ A2,
                                               const float* __restrict__ bases,
                                               const float* __restrict__ bias,
                                               float* __restrict__ out) {
    const int wt = blockIdx.x, ht = blockIdx.y, n = blockIdx.z;
    const int w0 = wt * 32, h0 = ht * 3;
    __shared__ ushort sFeat[176 * 128];     // 45 KB
    __shared__ ushort sFm[176 * FMT];       // 46.1 KB
    __shared__ float  sBa[54 * 96];         // 20.25 KB
    const int tid = threadIdx.x;

    for (int it = 0; it < 22; ++it) {
        int i = it * 512 + tid;
        if (i < 170 * 64) {
            int hp = i % 170;
            int cp = (i / 170) * 2;
            int hy2 = hp / 34, hx2 = hp - hy2 * 34;
            int gh = h0 - 1 + hy2, gw = w0 - 1 + hx2;
            unsigned v = 0u;
            if ((unsigned)gh < 96u && (unsigned)gw < 96u) {
                const float* fp = &feat[((size_t)(n * CC + cp)) * HW + gh * WW_ + gw];
                v = (unsigned)f2bf(fp[0]) | ((unsigned)f2bf(fp[HW]) << 16);
            }
            int idx = hp * 128 + (((cp >> 3) ^ (hp & 15)) << 3) + (cp & 7);
            *(unsigned*)&sFeat[idx] = v;
        }
    }
    for (int j = tid; j < 6 * 64; j += 512) ((unsigned*)&sFeat[170 * 128])[j] = 0u;
    for (int it = 0; it < 11; ++it) {
        int i = it * 512 + tid;
        if (i < 54 * 96) {
            int j = i / 96, p = i - j * 96;
            int hy = p >> 5, wx = p & 31;
            sBa[i] = bases[((size_t)(n * 54 + j)) * HW + (h0 + hy) * WW_ + w0 + wx];
        }
    }
    __syncthreads();

    const int l  = tid & 63, wv = tid >> 6;
    const int lx = l & 15, cg = l >> 4;
    const int mg = wv & 1, ng = wv >> 1;
    const int nt = (ng == 3) ? 2 : 3;
    const int co_l = tid & 127;
    const int g4   = tid >> 7;
    const int wx0  = g4 * 8;

    float accO[3][8];
#pragma unroll
    for (int a = 0; a < 3; ++a)
#pragma unroll
        for (int p = 0; p < 8; ++p) accO[a][p] = 0.f;

    const bf16x8* Ap = (const bf16x8*)A2;
    const f32x4 z = {0.f, 0.f, 0.f, 0.f};

    for (int m = 0; m < 6; ++m) {
        __syncthreads();

        f32x4 acc[4][3];
#pragma unroll
        for (int mi = 0; mi < 4; ++mi)
#pragma unroll
            for (int ti = 0; ti < 3; ++ti) acc[mi][ti] = z;

#pragma unroll
        for (int ks = 0; ks < 4; ++ks) {
            bf16x8 a[4];
#pragma unroll
            for (int mi = 0; mi < 4; ++mi)
                a[mi] = Ap[((size_t)((m * 4 + ks) * 8 + mg * 4 + mi)) * 64 + l];
            const int gsw = (ks * 4 + cg) ^ lx;
#pragma unroll
            for (int ti = 0; ti < 3; ++ti) {
                if (ti < nt) {
                    int px = (ng * 3 + ti) * 16 + lx;
                    bf16x8 b = *(const bf16x8*)&sFeat[px * 128 + (gsw << 3)];
#pragma unroll
                    for (int mi = 0; mi < 4; ++mi)
                        acc[mi][ti] = __builtin_amdgcn_mfma_f32_16x16x32_bf16(a[mi], b, acc[mi][ti], 0, 0, 0);
                }
            }
        }
#pragma unroll
        for (int ti = 0; ti < 3; ++ti) {
            if (ti < nt) {
                int px = (ng * 3 + ti) * 16 + lx;
#pragma unroll
                for (int mi = 0; mi < 4; ++mi) {
                    int co = (mg * 4 + mi) * 16 + cg * 4;
                    unsigned v0 = (unsigned)f2bf(acc[mi][ti][0]) | ((unsigned)f2bf(acc[mi][ti][1]) << 16);
                    unsigned v1 = (unsigned)f2bf(acc[mi][ti][2]) | ((unsigned)f2bf(acc[mi][ti][3]) << 16);
                    *(unsigned*)&sFm[px * FMT + co]     = v0;
                    *(unsigned*)&sFm[px * FMT + co + 2] = v1;
                }
            }
        }
        __syncthreads();

#pragma unroll
        for (int hy = 0; hy < 3; ++hy) {
#pragma unroll
            for (int dy = 0; dy < 3; ++dy) {
                const int hrow = (hy + dy) * 34 + wx0;
                float rr[10];
#pragma unroll
                for (int x = 0; x < 10; ++x)
                    rr[x] = bf2f(sFm[(hrow + x) * FMT + co_l]);
#pragma unroll
                for (int dx = 0; dx < 3; ++dx) {
                    const float* sb = &sBa[(m * 9 + dy * 3 + dx) * 96 + hy * 32 + wx0];
#pragma unroll
                    for (int p = 0; p < 8; ++p)
                        accO[hy][p] = fmaf(sb[p], rr[p + dx], accO[hy][p]);
                }
            }
        }
    }

    const float bv = bias[co_l];
#pragma unroll
    for (int hy = 0; hy < 3; ++hy) {
        float4 o0, o1;
        o0.x = accO[hy][0] + bv; o0.y = accO[hy][1] + bv;
        o0.z = accO[hy][2] + bv; o0.w = accO[hy][3] + bv;
        o1.x = accO[hy][4] + bv; o1.y = accO[hy][5] + bv;
        o1.z = accO[hy][6] + bv; o1.w = accO[hy][7] + bv;
        float* op = &out[((size_t)(n * CC + co_l)) * HW + (h0 + hy) * WW_ + w0 + wx0];
        *(float4*)op       = o0;
        *(float4*)(op + 4) = o1;
    }
}

// ---------------------------------------------------------------------------
extern "C" void kernel_launch(void* const* d_in, const int* in_sizes, int n_in,
                              void* d_out, int out_size, void* d_ws, size_t ws_size,
                              hipStream_t stream) {
    const float* feat = (const float*)d_in[0];
    const float* wgt  = (const float*)d_in[1];
    const float* w1   = (const float*)d_in[2];
    const float* b1   = (const float*)d_in[3];
    const float* w2   = (const float*)d_in[4];
    const float* b2   = (const float*)d_in[5];
    const float* bbuf = (const float*)d_in[6];
    const float* coef = (const float*)d_in[7];
    const float* bias = (const float*)d_in[8];
    float* out = (float*)d_out;

    float* ws = (float*)d_ws;
    ushort* A1   = (ushort*)(ws + OFF_A1);
    ushort* A2   = (ushort*)(ws + OFF_A2);
    float* bases = ws + OFF_BASES;
    ushort* hmid = (ushort*)(ws + OFF_HMID);

    k_prep  <<<dim3(1248),      dim3(256), 0, stream>>>(w1, coef, A1, A2);
    k_conv1m<<<dim3(6, 6, NN),  dim3(256), 0, stream>>>(feat, wgt, A1, b1, hmid);
    k_conv2 <<<dim3(36, NN),    dim3(256), 0, stream>>>(hmid, w2, b2, bbuf, bases);
    k_fused <<<dim3(3, 32, NN), dim3(512), 0, stream>>>(feat, A2, bases, bias, out);
}

// Round 7
// 334.142 us; speedup vs baseline: 5.0019x; 1.0804x over previous
//
#include <hip/hip_runtime.h>

// Problem constants
#define NN   8
#define CC   128
#define CWW  64
#define CIN  192
#define HH   96
#define WW_  96
#define HW   (HH*WW_)      // 9216
#define NB   6
#define TEM  6
#define B36  36
#define KF   768

typedef __attribute__((ext_vector_type(8))) short bf16x8;
typedef __attribute__((ext_vector_type(4))) float f32x4;

// workspace layout (float offsets)
#define OFF_A1     0           // 221184 ushorts = 110592 floats
#define OFF_A2     110592      // 98304 ushorts = 49152 floats
#define OFF_BASES  159744      // 8*54*9216 ushorts (bf16 now)
#define OFF_HMID   4141056     // 8*128*9216 ushorts

__device__ inline ushort f2bf(float f) {
    union { float f; unsigned u; } x; x.f = f;
    unsigned r = x.u + 0x7FFFu + ((x.u >> 16) & 1u);
    return (ushort)(r >> 16);
}
__device__ inline float bf2f(ushort h) {
    union { unsigned u; float f; } t; t.u = ((unsigned)h) << 16; return t.f;
}
__device__ inline float fast_tanh(float x) {
    x = fminf(fmaxf(x, -15.f), 15.f);
    float e = __expf(2.f * x);
    float r;
    asm volatile("v_rcp_f32 %0, %1" : "=v"(r) : "v"(e + 1.f));
    return (e - 1.f) * r;
}

// ---------------------------------------------------------------------------
// Prep: pack conv1 weights (ks = kc*9+tap) and coef into MFMA fragment order.
__global__ __launch_bounds__(256) void k_prep(const float* __restrict__ w1,
                                              const float* __restrict__ coef,
                                              ushort* __restrict__ A1,
                                              ushort* __restrict__ A2) {
    int i = blockIdx.x * 256 + threadIdx.x;
    if (i < 221184) {
        int j = i & 7, l = (i >> 3) & 63, mf = (i >> 9) & 7, ks = i >> 12; // ks 0..53
        int kc = ks / 9, tap = ks - kc * 9;
        int co = mf * 16 + (l & 15);
        int ci = kc * 32 + 8 * (l >> 4) + j;
        A1[i] = f2bf(w1[(co * CIN + ci) * 9 + tap]);
    } else {
        int t = i - 221184;
        if (t < 98304) {
            int j = t & 7, l = (t >> 3) & 63, cf = (t >> 9) & 7, r = t >> 12; // r 0..23
            int ks = r & 3, m = r >> 2;
            int co = cf * 16 + (l & 15);
            int ci = ks * 32 + 8 * (l >> 4) + j;
            A2[t] = f2bf(coef[co * KF + ci * 6 + m]);
        }
    }
}

// ---------------------------------------------------------------------------
// conv1 via MFMA (unchanged from R4).
#define SBS 40
__global__ __launch_bounds__(256, 2) void k_conv1m(const float* __restrict__ feat,
                                                   const float* __restrict__ wgt,
                                                   const ushort* __restrict__ A1,
                                                   const float* __restrict__ b1,
                                                   ushort* __restrict__ hmid) {
    const int w0 = blockIdx.x * 16, h0 = blockIdx.y * 16, n = blockIdx.z;
    __shared__ ushort sB[2][324 * SBS];
    __shared__ ushort sA[2][4096];
    const int tid = threadIdx.x;
    const int l = tid & 63, wv = tid >> 6, lx = l & 15, cg = l >> 4;

    f32x4 acc[8][4];
    const f32x4 z = {0.f, 0.f, 0.f, 0.f};
#pragma unroll
    for (int mf = 0; mf < 8; ++mf)
#pragma unroll
        for (int nf = 0; nf < 4; ++nf) acc[mf][nf] = z;

#pragma unroll 1
    for (int it = 0; it < 21; ++it) {
        int i = it * 256 + tid;
        if (i < 5184) {
            int cpair = i / 324, col = i - cpair * 324;
            int rp = col / 18, xl = col - rp * 18;
            int gh = h0 - 1 + rp, gw = w0 - 1 + xl;
            int cp = cpair * 2;
            unsigned v = 0u;
            if ((unsigned)gh < 96u && (unsigned)gw < 96u) {
                const float* fp = &feat[((size_t)(n * CC + cp)) * HW + gh * WW_ + gw];
                v = (unsigned)f2bf(fp[0]) | ((unsigned)f2bf(fp[HW]) << 16);
            }
            *(unsigned*)&sB[0][col * SBS + cp] = v;
        }
    }
    {
        const uint4* src = (const uint4*)A1;
        uint4 v0 = src[tid], v1 = src[256 + tid];
        ((uint4*)&sA[0][0])[tid] = v0;
        ((uint4*)&sA[0][0])[256 + tid] = v1;
    }
    __syncthreads();

#pragma unroll 1
    for (int kc = 0; kc < 6; ++kc) {
#pragma unroll 1
        for (int tap = 0; tap < 9; ++tap) {
            const int ks = kc * 9 + tap;
            const int ab = ks & 1, bb = kc & 1;

            uint4 pA0, pA1;
            const bool doA = (ks < 53);
            if (doA) {
                const uint4* src = (const uint4*)(A1 + (size_t)(ks + 1) * 4096);
                pA0 = src[tid]; pA1 = src[256 + tid];
            }

            float pB0a = 0.f, pB0b = 0.f, pB1a = 0.f, pB1b = 0.f, pB2a = 0.f, pB2b = 0.f;
            int bo0 = -1, bo1 = -1, bo2 = -1;
            const bool doB = (kc < 5) && (tap < 7);
            if (doB) {
                const int nkc = kc + 1;
#pragma unroll
                for (int it = 0; it < 3; ++it) {
                    int i = (tap * 3 + it) * 256 + tid;
                    if (i < 5184) {
                        int cpair = i / 324, col = i - cpair * 324;
                        int rp = col / 18, xl = col - rp * 18;
                        int gh = h0 - 1 + rp, gw = w0 - 1 + xl;
                        int cp = cpair * 2, ci = nkc * 32 + cp;
                        float va = 0.f, vb = 0.f;
                        if ((unsigned)gh < 96u && (unsigned)gw < 96u) {
                            const float* fp = (ci < CC)
                                ? &feat[((size_t)(n * CC + ci)) * HW + gh * WW_ + gw]
                                : &wgt[((size_t)(n * CWW + ci - CC)) * HW + gh * WW_ + gw];
                            va = fp[0]; vb = fp[HW];
                        }
                        int off = col * SBS + cp;
                        if (it == 0)      { pB0a = va; pB0b = vb; bo0 = off; }
                        else if (it == 1) { pB1a = va; pB1b = vb; bo1 = off; }
                        else              { pB2a = va; pB2b = vb; bo2 = off; }
                    }
                }
            }

            bf16x8 afr[8];
#pragma unroll
            for (int mf = 0; mf < 8; ++mf)
                afr[mf] = *(const bf16x8*)&sA[ab][(mf * 64 + l) * 8];
            const int dy = tap / 3, dx = tap - dy * 3;
            bf16x8 bfr[4];
#pragma unroll
            for (int nf = 0; nf < 4; ++nf) {
                int col0 = (wv * 4 + nf + dy) * 18 + lx + dx;
                bfr[nf] = *(const bf16x8*)&sB[bb][col0 * SBS + 8 * cg];
            }
#pragma unroll
            for (int mf = 0; mf < 8; ++mf)
#pragma unroll
                for (int nf = 0; nf < 4; ++nf)
                    acc[mf][nf] = __builtin_amdgcn_mfma_f32_16x16x32_bf16(afr[mf], bfr[nf], acc[mf][nf], 0, 0, 0);

            if (doA) {
                uint4* d = (uint4*)&sA[ab ^ 1][0];
                d[tid] = pA0; d[256 + tid] = pA1;
            }
            if (doB) {
                ushort* nb = &sB[bb ^ 1][0];
                if (bo0 >= 0) *(unsigned*)&nb[bo0] = (unsigned)f2bf(pB0a) | ((unsigned)f2bf(pB0b) << 16);
                if (bo1 >= 0) *(unsigned*)&nb[bo1] = (unsigned)f2bf(pB1a) | ((unsigned)f2bf(pB1b) << 16);
                if (bo2 >= 0) *(unsigned*)&nb[bo2] = (unsigned)f2bf(pB2a) | ((unsigned)f2bf(pB2b) << 16);
            }
            __syncthreads();
        }
    }

#pragma unroll
    for (int mf = 0; mf < 8; ++mf)
#pragma unroll
        for (int nf = 0; nf < 4; ++nf) {
            const int h = h0 + wv * 4 + nf;
#pragma unroll
            for (int r = 0; r < 4; ++r) {
                int co = mf * 16 + cg * 4 + r;
                float x = acc[mf][nf][r] + b1[co];
                hmid[((size_t)(n * CC + co) * HH + h) * WW_ + w0 + lx] = f2bf(fast_tanh(x));
            }
        }
}

// ---------------------------------------------------------------------------
// conv2 (1x1, 128->36) + tanh + basis mix (36 -> 54). bases now bf16.
__global__ __launch_bounds__(256) void k_conv2(const ushort* __restrict__ hmid,
                                               const float* __restrict__ w2,
                                               const float* __restrict__ b2,
                                               const float* __restrict__ bbuf,
                                               ushort* __restrict__ bases) {
    __shared__ float sW2[B36 * CC];
    __shared__ float sBB[TEM * 9];
    for (int i = threadIdx.x; i < B36 * CC; i += 256) sW2[i] = w2[i];
    if (threadIdx.x < TEM * 9) sBB[threadIdx.x] = bbuf[threadIdx.x];
    __syncthreads();

    const int n   = blockIdx.y;
    const int pix = blockIdx.x * 256 + threadIdx.x;

    float a[B36];
#pragma unroll
    for (int k = 0; k < B36; ++k) a[k] = b2[k];

    const ushort* hp = &hmid[(size_t)(n * CC) * HW + pix];
    for (int c = 0; c < CC; ++c) {
        float hv = bf2f(hp[c * HW]);
#pragma unroll
        for (int k = 0; k < B36; ++k) a[k] = fmaf(hv, sW2[k * CC + c], a[k]);
    }
#pragma unroll
    for (int k = 0; k < B36; ++k) a[k] = fast_tanh(a[k]);

    ushort* bp = &bases[(size_t)(n * 54) * HW + pix];
#pragma unroll
    for (int m = 0; m < NB; ++m) {
#pragma unroll
        for (int ll = 0; ll < 9; ++ll) {
            float s = 0.f;
#pragma unroll
            for (int t = 0; t < TEM; ++t) s = fmaf(a[m * TEM + t], sBB[t * 9 + ll], s);
            bp[(m * 9 + ll) * HW] = f2bf(s);
        }
    }
}

// ---------------------------------------------------------------------------
// Fused F-GEMM + dynamic combine, v2: 16x3 out px tile (halo 18x5=90),
// 256 thr / 4 waves, 59.9 KB LDS -> 2 blocks/CU for cross-block phase overlap.
// Combine: thread owns a co-pair (u32 LDS reads), 5-row sweep with hy+dy==r.
#define FMT2 130
__global__ __launch_bounds__(256, 2) void k_fused(const float* __restrict__ feat,
                                                  const ushort* __restrict__ A2,
                                                  const ushort* __restrict__ bases,
                                                  const float* __restrict__ bias,
                                                  float* __restrict__ out) {
    const int wt = blockIdx.x, ht = blockIdx.y, n = blockIdx.z;
    const int w0 = wt * 16, h0 = ht * 3;
    __shared__ ushort sFeat[96 * 128];     // 24576 B (rows 90..95 zero)
    __shared__ ushort sFm[96 * FMT2];      // 24960 B
    __shared__ float  sBa[54 * 48];        // 10368 B
    const int tid = threadIdx.x;

    // ---- stage feat halo: 90 halo px x 64 ci-pairs, XOR-swizzled bf16
#pragma unroll 1
    for (int it = 0; it < 23; ++it) {
        int i = it * 256 + tid;
        if (i < 5760) {
            int cp2 = i / 90;
            int hp  = i - cp2 * 90;
            int cp  = cp2 * 2;
            int hy2 = hp / 18, hx2 = hp - hy2 * 18;
            int gh = h0 - 1 + hy2, gw = w0 - 1 + hx2;
            unsigned v = 0u;
            if ((unsigned)gh < 96u && (unsigned)gw < 96u) {
                const float* fp = &feat[((size_t)(n * CC + cp)) * HW + gh * WW_ + gw];
                v = (unsigned)f2bf(fp[0]) | ((unsigned)f2bf(fp[HW]) << 16);
            }
            int idx = hp * 128 + (((cp >> 3) ^ (hp & 15)) << 3) + (cp & 7);
            *(unsigned*)&sFeat[idx] = v;
        }
    }
    // zero pad rows 90..95
#pragma unroll
    for (int it = 0; it < 2; ++it) {
        int i = it * 256 + tid;
        if (i < 384) ((unsigned*)&sFeat[90 * 128])[i] = 0u;
    }
    // stage bases tile (54 x 48, bf16 -> f32)
#pragma unroll 1
    for (int it = 0; it < 11; ++it) {
        int i = it * 256 + tid;
        if (i < 54 * 48) {
            int j = i / 48, p = i - j * 48;
            int hy = p >> 4, wx = p & 15;
            sBa[i] = bf2f(bases[((size_t)(n * 54 + j)) * HW + (h0 + hy) * WW_ + w0 + wx]);
        }
    }
    __syncthreads();

    const int l  = tid & 63, wv = tid >> 6;
    const int lx = l & 15, cg = l >> 4;
    const int mg = wv & 1, ng = wv >> 1;    // MFMA: co-half, px-tile-triple
    const int cp = tid & 63;                // combine: co-pair (co = 2cp, 2cp+1)
    const int g4 = tid >> 6;                // combine: w-strip base = g4*4

    float accO[3][2][4];
#pragma unroll
    for (int hy = 0; hy < 3; ++hy)
#pragma unroll
        for (int j = 0; j < 2; ++j)
#pragma unroll
            for (int p = 0; p < 4; ++p) accO[hy][j][p] = 0.f;

    const bf16x8* Ap = (const bf16x8*)A2;
    const f32x4 z = {0.f, 0.f, 0.f, 0.f};

#pragma unroll 1
    for (int m = 0; m < 6; ++m) {
        __syncthreads();        // sFm free (previous combine done)

        // ---- MFMA: F_m over the 96-px (padded) halo tile
        f32x4 acc[4][3];
#pragma unroll
        for (int mi = 0; mi < 4; ++mi)
#pragma unroll
            for (int ti = 0; ti < 3; ++ti) acc[mi][ti] = z;

#pragma unroll
        for (int ks = 0; ks < 4; ++ks) {
            bf16x8 a[4];
#pragma unroll
            for (int mi = 0; mi < 4; ++mi)
                a[mi] = Ap[((size_t)((m * 4 + ks) * 8 + mg * 4 + mi)) * 64 + l];
            const int gsw = ((ks * 4 + cg) ^ lx) << 3;
#pragma unroll
            for (int ti = 0; ti < 3; ++ti) {
                int px = (ng * 3 + ti) * 16 + lx;
                bf16x8 b = *(const bf16x8*)&sFeat[px * 128 + gsw];
#pragma unroll
                for (int mi = 0; mi < 4; ++mi)
                    acc[mi][ti] = __builtin_amdgcn_mfma_f32_16x16x32_bf16(a[mi], b, acc[mi][ti], 0, 0, 0);
            }
        }
        // write F_m -> sFm. D: col(px)=lx, row(co)=cg*4+r
#pragma unroll
        for (int ti = 0; ti < 3; ++ti) {
            int px = (ng * 3 + ti) * 16 + lx;
#pragma unroll
            for (int mi = 0; mi < 4; ++mi) {
                int co = (mg * 4 + mi) * 16 + cg * 4;
                unsigned v0 = (unsigned)f2bf(acc[mi][ti][0]) | ((unsigned)f2bf(acc[mi][ti][1]) << 16);
                unsigned v1 = (unsigned)f2bf(acc[mi][ti][2]) | ((unsigned)f2bf(acc[mi][ti][3]) << 16);
                *(unsigned*)&sFm[px * FMT2 + co]     = v0;
                *(unsigned*)&sFm[px * FMT2 + co + 2] = v1;
            }
        }
        __syncthreads();        // F_m ready

        // ---- combine: sweep 5 halo rows once; (hy,dy) pairs with hy+dy==r
#pragma unroll
        for (int r = 0; r < 5; ++r) {
            float rowv[6][2];
#pragma unroll
            for (int x = 0; x < 6; ++x) {
                int hp = r * 18 + g4 * 4 + x;
                unsigned u = *(const unsigned*)&sFm[hp * FMT2 + cp * 2];
                rowv[x][0] = bf2f((ushort)(u & 0xffffu));
                rowv[x][1] = bf2f((ushort)(u >> 16));
            }
#pragma unroll
            for (int hy = 0; hy < 3; ++hy) {
                const int dy = r - hy;
                if (dy < 0 || dy > 2) continue;
#pragma unroll
                for (int dx = 0; dx < 3; ++dx) {
                    const float* sb = &sBa[(m * 9 + dy * 3 + dx) * 48 + hy * 16 + g4 * 4];
#pragma unroll
                    for (int p = 0; p < 4; ++p) {
                        float bv = sb[p];
                        accO[hy][0][p] = fmaf(bv, rowv[p + dx][0], accO[hy][0][p]);
                        accO[hy][1][p] = fmaf(bv, rowv[p + dx][1], accO[hy][1][p]);
                    }
                }
            }
        }
    }

    // ---- epilogue: bias + float4 stores (w-contiguous per thread)
    const float bv0 = bias[2 * cp], bv1 = bias[2 * cp + 1];
#pragma unroll
    for (int hy = 0; hy < 3; ++hy)
#pragma unroll
        for (int j = 0; j < 2; ++j) {
            const int co = 2 * cp + j;
            const float bb = j ? bv1 : bv0;
            float4 o;
            o.x = accO[hy][j][0] + bb; o.y = accO[hy][j][1] + bb;
            o.z = accO[hy][j][2] + bb; o.w = accO[hy][j][3] + bb;
            *(float4*)&out[((size_t)(n * CC + co)) * HW + (h0 + hy) * WW_ + w0 + g4 * 4] = o;
        }
}

// ---------------------------------------------------------------------------
extern "C" void kernel_launch(void* const* d_in, const int* in_sizes, int n_in,
                              void* d_out, int out_size, void* d_ws, size_t ws_size,
                              hipStream_t stream) {
    const float* feat = (const float*)d_in[0];
    const float* wgt  = (const float*)d_in[1];
    const float* w1   = (const float*)d_in[2];
    const float* b1   = (const float*)d_in[3];
    const float* w2   = (const float*)d_in[4];
    const float* b2   = (const float*)d_in[5];
    const float* bbuf = (const float*)d_in[6];
    const float* coef = (const float*)d_in[7];
    const float* bias = (const float*)d_in[8];
    float* out = (float*)d_out;

    float* ws = (float*)d_ws;
    ushort* A1    = (ushort*)(ws + OFF_A1);
    ushort* A2    = (ushort*)(ws + OFF_A2);
    ushort* bases = (ushort*)(ws + OFF_BASES);
    ushort* hmid  = (ushort*)(ws + OFF_HMID);

    k_prep  <<<dim3(1248),      dim3(256), 0, stream>>>(w1, coef, A1, A2);
    k_conv1m<<<dim3(6, 6, NN),  dim3(256), 0, stream>>>(feat, wgt, A1, b1, hmid);
    k_conv2 <<<dim3(36, NN),    dim3(256), 0, stream>>>(hmid, w2, b2, bbuf, bases);
    k_fused <<<dim3(6, 32, NN), dim3(256), 0, stream>>>(feat, A2, bases, bias, out);
}